// Round 4
// baseline (5122.248 us; speedup 1.0000x reference)
//
#include <hip/hip_runtime.h>

// ---------- types ----------
typedef short short8 __attribute__((ext_vector_type(8)));   // 8 bf16 in 4 VGPRs
typedef float f32x4 __attribute__((ext_vector_type(4)));    // MFMA accumulator

#define N_USERS 4096
#define T_STEPS 64
#define SKEP 768
#define HDIM 256
#define KROLE 64

// ---------- helpers ----------
__device__ __forceinline__ unsigned short f2bfs(float f) {
  unsigned int u = __builtin_bit_cast(unsigned int, f);
  u += 0x7fffu + ((u >> 16) & 1u);          // round-to-nearest-even
  return (unsigned short)(u >> 16);
}
__device__ __forceinline__ float bf2f(unsigned short b) {
  unsigned int u = ((unsigned int)b) << 16;
  return __builtin_bit_cast(float, u);
}
__device__ __forceinline__ short8 pack8(float4 a, float4 b) {
  short8 o;
  o[0] = (short)f2bfs(a.x); o[1] = (short)f2bfs(a.y);
  o[2] = (short)f2bfs(a.z); o[3] = (short)f2bfs(a.w);
  o[4] = (short)f2bfs(b.x); o[5] = (short)f2bfs(b.y);
  o[6] = (short)f2bfs(b.z); o[7] = (short)f2bfs(b.w);
  return o;
}
__device__ __forceinline__ float sigm(float x) { return 1.0f / (1.0f + __expf(-x)); }
__device__ __forceinline__ float tanh_(float x) { return 1.0f - 2.0f / (1.0f + __expf(2.0f * x)); }

// ---------- prep: W_cat = [W_hh | W_ih] bf16, rows permuted gate-interleaved ----------
// gate-col c: gate gi=(c>>4)&3, unit u=((c>>6)<<4)|(c&15) -> orig row gi*256+u
__global__ __launch_bounds__(256) void k_prep(
    const float* __restrict__ Wih, const float* __restrict__ Whh,
    const float* __restrict__ bih, const float* __restrict__ bhh,
    unsigned short* __restrict__ wcat, float* __restrict__ bias)
{
  int c = blockIdx.x;
  int gi = (c >> 4) & 3;
  int u = ((c >> 6) << 4) | (c & 15);
  int orig = gi * HDIM + u;
  for (int k = threadIdx.x; k < 1024; k += 256) {
    float w = (k < HDIM) ? Whh[(size_t)orig * HDIM + k]
                         : Wih[(size_t)orig * SKEP + (k - HDIM)];
    wcat[(size_t)c * 1024 + k] = f2bfs(w);
  }
  if (threadIdx.x == 0) bias[c] = bih[orig] + bhh[orig];
}

// ---------- k_bigx (t-major): X = hist[:, t, :] @ W_ih^T for all t ----------
// Block = (t, Mtu, Nt): 128 users at fixed t x 128 gate-cols. Output layout:
// slab = ((t*32+Mtu)*8+Nt)*16384 ushorts; thread stores its 32 accs at
// slab + tid*32, order idx = mi*16 + q*4 + nj  (matches k_lstm's reader 1:1).
__global__ __launch_bounds__(512) void k_bigx(
    const float* __restrict__ hist,
    const unsigned short* __restrict__ wcat,
    unsigned short* __restrict__ X)
{
  __shared__ __align__(16) unsigned char smem[65536];
  unsigned char* const A0 = smem;
  unsigned char* const B0 = smem + 16384;
  unsigned char* const A1 = smem + 32768;
  unsigned char* const B1 = smem + 49152;

  const int tid = threadIdx.x;
  const int lane = tid & 63;
  const int wid = tid >> 6;
  const int wr = wid >> 1;       // 0..3
  const int wc = wid & 1;        // 0..1
  const int lr = lane & 15;
  const int lg = lane >> 4;

  const int d = blockIdx.x;
  const int x = d & 7;
  const int Nt = (d >> 3) & 7;
  const int g = ((d >> 6) << 3) | x;          // 0..2047 group id
  const int t = g >> 5;                       // 0..63
  const int Mtu = g & 31;                     // 0..31
  const int n0 = Mtu * 128;
  const int c0 = Nt * 128;

  f32x4 acc[2][4];
#pragma unroll
  for (int mi = 0; mi < 2; ++mi)
#pragma unroll
    for (int nj = 0; nj < 4; ++nj) acc[mi][nj] = f32x4{0.f, 0.f, 0.f, 0.f};

  const int rr = tid >> 3;                    // 0..63
  const int cl = (tid & 7) ^ (rr & 7);        // XOR swizzle chunk
  const size_t hA0 = ((size_t)(n0 + rr) * T_STEPS + t) * SKEP + (size_t)cl * 8;
  const size_t hA1 = ((size_t)(n0 + rr + 64) * T_STEPS + t) * SKEP + (size_t)cl * 8;
  const size_t wB0 = (size_t)(c0 + rr) * 1024 + 256 + (size_t)cl * 8;
  const size_t wB1 = (size_t)(c0 + rr + 64) * 1024 + 256 + (size_t)cl * 8;
  const int dst0 = tid * 16, dst1 = tid * 16 + 8192;

  // prologue: stage kt=0
  {
    const float* p0 = hist + hA0;
    const float* p1 = hist + hA1;
    float4 f00 = *(const float4*)p0, f01 = *(const float4*)(p0 + 4);
    float4 f10 = *(const float4*)p1, f11 = *(const float4*)(p1 + 4);
    short8 b0 = *(const short8*)(wcat + wB0);
    short8 b1 = *(const short8*)(wcat + wB1);
    *(short8*)(A0 + dst0) = pack8(f00, f01);
    *(short8*)(A0 + dst1) = pack8(f10, f11);
    *(short8*)(B0 + dst0) = b0;
    *(short8*)(B0 + dst1) = b1;
  }
  __syncthreads();

  for (int kt = 0; kt < 12; ++kt) {
    unsigned char* curA = (kt & 1) ? A1 : A0;
    unsigned char* curB = (kt & 1) ? B1 : B0;
    unsigned char* nxtA = (kt & 1) ? A0 : A1;
    unsigned char* nxtB = (kt & 1) ? B0 : B1;
    const int kn = kt + 1;
    const bool have = (kn < 12);

    float4 f00, f01, f10, f11;
    short8 sb0, sb1;
    if (have) {
      const float* p0 = hist + hA0 + (size_t)kn * 64;
      const float* p1 = hist + hA1 + (size_t)kn * 64;
      f00 = *(const float4*)p0; f01 = *(const float4*)(p0 + 4);
      f10 = *(const float4*)p1; f11 = *(const float4*)(p1 + 4);
      sb0 = *(const short8*)(wcat + wB0 + (size_t)kn * 64);
      sb1 = *(const short8*)(wcat + wB1 + (size_t)kn * 64);
    }

#pragma unroll
    for (int ks = 0; ks < 2; ++ks) {
      short8 av[2], bv[4];
#pragma unroll
      for (int mi = 0; mi < 2; ++mi) {
        int r = wr * 32 + mi * 16 + lr;
        int c = ks * 4 + lg;
        int ph = c ^ (r & 7);
        av[mi] = *(const short8*)(curA + r * 128 + ph * 16);
      }
#pragma unroll
      for (int nj = 0; nj < 4; ++nj) {
        int r = wc * 64 + nj * 16 + lr;
        int c = ks * 4 + lg;
        int ph = c ^ (r & 7);
        bv[nj] = *(const short8*)(curB + r * 128 + ph * 16);
      }
#pragma unroll
      for (int mi = 0; mi < 2; ++mi)
#pragma unroll
        for (int nj = 0; nj < 4; ++nj)
          acc[mi][nj] = __builtin_amdgcn_mfma_f32_16x16x32_bf16(av[mi], bv[nj], acc[mi][nj], 0, 0, 0);
    }

    if (have) {
      *(short8*)(nxtA + dst0) = pack8(f00, f01);
      *(short8*)(nxtA + dst1) = pack8(f10, f11);
      *(short8*)(nxtB + dst0) = sb0;
      *(short8*)(nxtB + dst1) = sb1;
    }
    __syncthreads();
  }

  // epilogue: pack 32 accs -> one contiguous 64 B chunk per thread
  unsigned short ob[32];
#pragma unroll
  for (int mi = 0; mi < 2; ++mi)
#pragma unroll
    for (int q = 0; q < 4; ++q)
#pragma unroll
      for (int nj = 0; nj < 4; ++nj)
        ob[mi * 16 + q * 4 + nj] = f2bfs(acc[mi][nj][q]);

  const size_t slab = (((size_t)t * 32 + Mtu) * 8 + Nt) * 16384 + (size_t)tid * 32;
#pragma unroll
  for (int j2 = 0; j2 < 4; ++j2)
    *(short8*)(X + slab + j2 * 8) = *(const short8*)(ob + j2 * 8);
}

// ---------- k_lstm: persistent, all 64 steps in one kernel ----------
// 256 blocks (Mt 0..31 x Nt 0..7), 512 threads, 128 KB LDS -> 1 block/CU.
// c-state and h_prev in registers; W_hh tile LDS-resident; h exchanged via
// global ping-pong + per-Mt fabric counter. Spin = RELAXED (no inv storm);
// one acquire fence per step by all waves; one release fence before signal.
__global__ __launch_bounds__(512, 1) void k_lstm(
    const unsigned short* __restrict__ X,
    unsigned short* __restrict__ h0,
    unsigned short* __restrict__ h1,
    const unsigned short* __restrict__ wcat,
    const float* __restrict__ bias,
    const int* __restrict__ lengths,
    unsigned int* __restrict__ ctr)
{
  __shared__ __align__(16) unsigned char smem[131072];
  unsigned char* const Bs = smem;            // 64 KB: 128 gatecols x 512 B (XOR-swizzled)
  unsigned char* const As = smem + 65536;    // 64 KB: 128 users   x 512 B (XOR-swizzled)

  const int tid = threadIdx.x;
  const int lane = tid & 63;
  const int wid = tid >> 6;
  const int wr = wid >> 1, wc = wid & 1;
  const int lr = lane & 15, lg = lane >> 4;
  const int d = blockIdx.x;
  const int Mt = d & 31, Nt = d >> 5;        // d%8 == Mt%8: stripe shares XCD
  const int n0 = Mt * 128, c0 = Nt * 128;
  unsigned int* const ctrp = ctr + Mt * 16;  // 64 B padded counters

  // ---- stage B once: g-linear (coalesced global, conflict-free LDS) ----
#pragma unroll
  for (int j = 0; j < 8; ++j) {
    int g = wid * 512 + j * 64 + lane;       // chunk id 0..4095
    int r = g >> 5, c = g & 31;
    short8 v = *(const short8*)(wcat + (size_t)(c0 + r) * 1024 + c * 8);
    *(short8*)(Bs + r * 512 + ((c ^ (r & 7)) << 4)) = v;
  }

  // ---- per-thread constants ----
  float bs4[4];
#pragma unroll
  for (int gi2 = 0; gi2 < 4; ++gi2) bs4[gi2] = bias[c0 + wc * 64 + gi2 * 16 + lr];
  const int unitg = Nt * 32 + wc * 16 + lr;
  int len8[2][4];
#pragma unroll
  for (int mi = 0; mi < 2; ++mi)
#pragma unroll
    for (int q = 0; q < 4; ++q)
      len8[mi][q] = lengths[n0 + wr * 32 + mi * 16 + lg * 4 + q];

  float cc8[2][4] = {{0.f, 0.f, 0.f, 0.f}, {0.f, 0.f, 0.f, 0.f}};
  unsigned short hp8[2][4] = {{0, 0, 0, 0}, {0, 0, 0, 0}};

#pragma unroll 1
  for (int t = 0; t < T_STEPS; ++t) {
    // X prefetch (independent of h; overlaps the spin-wait)
    short8 xv0, xv1, xv2, xv3;
    {
      const unsigned short* xp =
          X + (((size_t)t * 32 + Mt) * 8 + Nt) * 16384 + (size_t)tid * 32;
      xv0 = *(const short8*)(xp);
      xv1 = *(const short8*)(xp + 8);
      xv2 = *(const short8*)(xp + 16);
      xv3 = *(const short8*)(xp + 24);
    }

    if (t > 0) {
      if (tid == 0) {
        const unsigned tgt = 8u * (unsigned)t;
        while (__hip_atomic_load(ctrp, __ATOMIC_RELAXED, __HIP_MEMORY_SCOPE_AGENT) < tgt)
          __builtin_amdgcn_s_sleep(2);
      }
      __syncthreads();
      __builtin_amdgcn_fence(__ATOMIC_ACQUIRE, "agent");   // one inv/step/wave
    }

    const unsigned short* hin = (t & 1) ? h1 : h0;
    unsigned short* hout = (t & 1) ? h0 : h1;

    // ---- stage A (h tile, contiguous 64 KB): g-linear, conflict-free ----
    {
      const unsigned short* hbase = hin + (size_t)n0 * HDIM;
#pragma unroll
      for (int j = 0; j < 8; ++j) {
        int g = wid * 512 + j * 64 + lane;
        int r = g >> 5, c = g & 31;
        short8 v = *(const short8*)(hbase + (size_t)g * 8);
        *(short8*)(As + r * 512 + ((c ^ (r & 7)) << 4)) = v;
      }
    }
    __syncthreads();

    // ---- GEMM: gates += h @ W_hh^T ----
    f32x4 acc[2][4];
#pragma unroll
    for (int mi = 0; mi < 2; ++mi)
#pragma unroll
      for (int nj = 0; nj < 4; ++nj) acc[mi][nj] = f32x4{0.f, 0.f, 0.f, 0.f};

#pragma unroll
    for (int ks = 0; ks < 8; ++ks) {
      const int chunk = ks * 4 + lg;
      short8 av0, av1, bv[4];
      {
        int r = wr * 32 + lr;
        av0 = *(const short8*)(As + r * 512 + ((chunk ^ (r & 7)) << 4));
        r += 16;
        av1 = *(const short8*)(As + r * 512 + ((chunk ^ (r & 7)) << 4));
      }
#pragma unroll
      for (int nj = 0; nj < 4; ++nj) {
        int rB = wc * 64 + nj * 16 + lr;
        bv[nj] = *(const short8*)(Bs + rB * 512 + ((chunk ^ (rB & 7)) << 4));
      }
#pragma unroll
      for (int nj = 0; nj < 4; ++nj) {
        acc[0][nj] = __builtin_amdgcn_mfma_f32_16x16x32_bf16(av0, bv[nj], acc[0][nj], 0, 0, 0);
        acc[1][nj] = __builtin_amdgcn_mfma_f32_16x16x32_bf16(av1, bv[nj], acc[1][nj], 0, 0, 0);
      }
    }

    // ---- LSTM cell epilogue (c, h_prev in registers) ----
#pragma unroll
    for (int mi = 0; mi < 2; ++mi) {
#pragma unroll
      for (int q = 0; q < 4; ++q) {
        const int idx0 = mi * 16 + q * 4;           // 0,4,8,...,28
        const short8 xs = (idx0 < 8) ? xv0 : (idx0 < 16) ? xv1
                         : (idx0 < 24) ? xv2 : xv3;
        const int sb = idx0 & 7;                    // 0 or 4
        float gi_ = sigm(acc[mi][0][q] + bf2f((unsigned short)xs[sb + 0]) + bs4[0]);
        float gf_ = sigm(acc[mi][1][q] + bf2f((unsigned short)xs[sb + 1]) + bs4[1]);
        float gg_ = tanh_(acc[mi][2][q] + bf2f((unsigned short)xs[sb + 2]) + bs4[2]);
        float go_ = sigm(acc[mi][3][q] + bf2f((unsigned short)xs[sb + 3]) + bs4[3]);
        if (t < len8[mi][q]) {
          float cn = gf_ * cc8[mi][q] + gi_ * gg_;
          cc8[mi][q] = cn;
          hp8[mi][q] = f2bfs(go_ * tanh_(cn));
        }
        hout[(size_t)(n0 + wr * 32 + mi * 16 + lg * 4 + q) * HDIM + unitg] = hp8[mi][q];
      }
    }

    __builtin_amdgcn_fence(__ATOMIC_RELEASE, "agent");   // drain + wbL2, per wave
    __syncthreads();
    if (t < T_STEPS - 1 && tid == 0)
      __hip_atomic_fetch_add(ctrp, 1u, __ATOMIC_RELAXED, __HIP_MEMORY_SCOPE_AGENT);
  }
}

// ---------- Phase C1: s[n] = dot(cc[cid[n]], uv[n]) / sqrt(H) ----------
__global__ __launch_bounds__(256) void k_scores(
    const float* __restrict__ uv, const float* __restrict__ cc,
    const int* __restrict__ cid, float* __restrict__ s)
{
  int n = blockIdx.x * 4 + (threadIdx.x >> 6);
  int lane = threadIdx.x & 63;
  float4 a = *(const float4*)(uv + (size_t)n * HDIM + lane * 4);
  float4 b = *(const float4*)(cc + (size_t)cid[n] * HDIM + lane * 4);
  float dd = a.x * b.x + a.y * b.y + a.z * b.z + a.w * b.w;
  for (int off = 32; off; off >>= 1) dd += __shfl_down(dd, off);
  if (lane == 0) s[n] = dd * 0.0625f;   // 1/sqrt(256)
}

// ---------- Phase C2: segment softmax + role_senti ----------
__global__ __launch_bounds__(256) void k_role(
    const float* __restrict__ s, const int* __restrict__ cid,
    const unsigned short* __restrict__ hn, float* __restrict__ rs)
{
  __shared__ float sv[N_USERS];
  __shared__ int cv[N_USERS];
  __shared__ float red[256];
  const int k = blockIdx.x, tid = threadIdx.x;
  for (int i = tid; i < N_USERS; i += 256) { sv[i] = s[i]; cv[i] = cid[i]; }
  __syncthreads();
  float m = -3.4e38f;
  for (int i = tid; i < N_USERS; i += 256) if (cv[i] == k) m = fmaxf(m, sv[i]);
  red[tid] = m; __syncthreads();
  for (int st = 128; st; st >>= 1) { if (tid < st) red[tid] = fmaxf(red[tid], red[tid + st]); __syncthreads(); }
  const float smax = red[0];
  __syncthreads();
  float sum = 0.f;
  for (int i = tid; i < N_USERS; i += 256)
    if (cv[i] == k) { float e = __expf(sv[i] - smax); sv[i] = e; sum += e; }
  red[tid] = sum; __syncthreads();
  for (int st = 128; st; st >>= 1) { if (tid < st) red[tid] += red[tid + st]; __syncthreads(); }
  const float den = red[0];
  __syncthreads();
  float a = 0.f;
  for (int i = 0; i < N_USERS; ++i)
    if (cv[i] == k) a += sv[i] * bf2f(hn[(size_t)i * HDIM + tid]);
  rs[(size_t)k * HDIM + tid] = a / den;
}

// ---------- Phase D1: per-head MHA over roles ----------
__global__ __launch_bounds__(256) void k_mha(
    const float* __restrict__ rs,
    const float* __restrict__ Wq, const float* __restrict__ bq,
    const float* __restrict__ Wk, const float* __restrict__ bk,
    const float* __restrict__ Wv, const float* __restrict__ bv,
    float* __restrict__ attout)
{
  __shared__ float q[64][32], kk[64][32], v[64][32];
  __shared__ float att[64][64];
  const int h = blockIdx.x, tid = threadIdx.x;
  for (int idx = tid; idx < 2048; idx += 256) {
    int r = idx >> 5, dd2 = idx & 31;
    int wrow = h * 32 + dd2;
    float aq = bq[wrow], ak = bk[wrow], av = bv[wrow];
    const float* x = rs + (size_t)r * HDIM;
    const float* wq = Wq + (size_t)wrow * HDIM;
    const float* wk = Wk + (size_t)wrow * HDIM;
    const float* wv = Wv + (size_t)wrow * HDIM;
    for (int j = 0; j < HDIM; ++j) {
      float xv = x[j];
      aq += xv * wq[j]; ak += xv * wk[j]; av += xv * wv[j];
    }
    q[r][dd2] = aq; kk[r][dd2] = ak; v[r][dd2] = av;
  }
  __syncthreads();
  for (int idx = tid; idx < 4096; idx += 256) {
    int qr = idx >> 6, kr = idx & 63;
    float sc = 0.f;
    for (int dd2 = 0; dd2 < 32; ++dd2) sc += q[qr][dd2] * kk[kr][dd2];
    att[qr][kr] = sc * 0.17677669529663687f;   // 1/sqrt(32)
  }
  __syncthreads();
  if (tid < 64) {
    float m = -3.4e38f;
    for (int j = 0; j < 64; ++j) m = fmaxf(m, att[tid][j]);
    float sum = 0.f;
    for (int j = 0; j < 64; ++j) { float e = __expf(att[tid][j] - m); att[tid][j] = e; sum += e; }
    float inv = 1.f / sum;
    for (int j = 0; j < 64; ++j) att[tid][j] *= inv;
  }
  __syncthreads();
  for (int idx = tid; idx < 2048; idx += 256) {
    int r = idx >> 5, dd2 = idx & 31;
    float o = 0.f;
    for (int kr = 0; kr < 64; ++kr) o += att[r][kr] * v[kr][dd2];
    attout[(size_t)r * HDIM + h * 32 + dd2] = o;
  }
}

// ---------- Phase D2: mean over roles + Wo projection ----------
__global__ __launch_bounds__(256) void k_out(
    const float* __restrict__ attout, const float* __restrict__ Wo,
    const float* __restrict__ bo, float* __restrict__ out)
{
  __shared__ float m_s[256];
  const int tid = threadIdx.x;
  float mm = 0.f;
  for (int r = 0; r < 64; ++r) mm += attout[(size_t)r * HDIM + tid];
  m_s[tid] = mm * (1.0f / 64.0f);
  __syncthreads();
  float a = bo[tid];
  for (int j = 0; j < HDIM; ++j) a += m_s[j] * Wo[(size_t)tid * HDIM + j];
  out[tid] = a;
}

extern "C" void kernel_launch(void* const* d_in, const int* in_sizes, int n_in,
                              void* d_out, int out_size, void* d_ws, size_t ws_size,
                              hipStream_t stream) {
  const float* hist = (const float*)d_in[0];
  const float* uv   = (const float*)d_in[1];
  const float* cc   = (const float*)d_in[2];
  const float* Wih  = (const float*)d_in[3];
  const float* Whh  = (const float*)d_in[4];
  const float* bih  = (const float*)d_in[5];
  const float* bhh  = (const float*)d_in[6];
  const float* Wq   = (const float*)d_in[7];
  const float* bq   = (const float*)d_in[8];
  const float* Wk   = (const float*)d_in[9];
  const float* bk   = (const float*)d_in[10];
  const float* Wv   = (const float*)d_in[11];
  const float* bv   = (const float*)d_in[12];
  const float* Wo   = (const float*)d_in[13];
  const float* bo   = (const float*)d_in[14];
  const int* lengths = (const int*)d_in[15];
  const int* cid     = (const int*)d_in[16];
  float* out = (float*)d_out;

  unsigned char* ws = (unsigned char*)d_ws;
  unsigned short* hbuf0 = (unsigned short*)(ws);                         // 2 MB
  unsigned short* hbuf1 = (unsigned short*)(ws + (1u << 21));            // 2 MB
  unsigned int*   ctr   = (unsigned int*)  (ws + (2u << 21));            // 2 KB (64B-padded x32)
  unsigned short* wcat  = (unsigned short*)(ws + (2u << 21) + 4096);     // 2 MB
  float* bias   = (float*)(ws + (3u << 21) + 4096);                      // 4 KB
  float* sbuf   = bias + 1024;                                           // 16 KB
  float* rs     = sbuf + 4096;                                           // 64 KB
  float* attout = rs + 16384;                                            // 64 KB
  unsigned short* Xbuf = (unsigned short*)(ws + (16ull << 20));          // 512 MB
  const size_t need = (16ull << 20) + (size_t)N_USERS * T_STEPS * 1024 * 2;
  if (ws_size < need) return;

  hipMemsetAsync(hbuf0, 0, (size_t)N_USERS * HDIM * 2, stream);
  hipMemsetAsync(ctr, 0, 2048, stream);

  k_prep<<<1024, 256, 0, stream>>>(Wih, Whh, bih, bhh, wcat, bias);
  k_bigx<<<16384, 512, 0, stream>>>(hist, wcat, Xbuf);
  k_lstm<<<256, 512, 0, stream>>>(Xbuf, hbuf0, hbuf1, wcat, bias, lengths, ctr);
  // t=63 writes hbuf0 -> final h in hbuf0

  k_scores<<<1024, 256, 0, stream>>>(uv, cc, cid, sbuf);
  k_role<<<64, 256, 0, stream>>>(sbuf, cid, hbuf0, rs);
  k_mha<<<8, 256, 0, stream>>>(rs, Wq, bq, Wk, bk, Wv, bv, attout);
  k_out<<<1, 256, 0, stream>>>(attout, Wo, bo, out);
}

// Round 5
// 1592.252 us; speedup vs baseline: 3.2170x; 3.2170x over previous
//
#include <hip/hip_runtime.h>

// ---------- types ----------
typedef short short8 __attribute__((ext_vector_type(8)));   // 8 bf16 in 4 VGPRs
typedef float f32x4 __attribute__((ext_vector_type(4)));    // MFMA accumulator

#define N_USERS 4096
#define T_STEPS 64
#define SKEP 768
#define HDIM 256
#define KROLE 64

// ---------- helpers ----------
__device__ __forceinline__ unsigned short f2bfs(float f) {
  unsigned int u = __builtin_bit_cast(unsigned int, f);
  u += 0x7fffu + ((u >> 16) & 1u);          // round-to-nearest-even
  return (unsigned short)(u >> 16);
}
__device__ __forceinline__ float bf2f(unsigned short b) {
  unsigned int u = ((unsigned int)b) << 16;
  return __builtin_bit_cast(float, u);
}
__device__ __forceinline__ short8 pack8(float4 a, float4 b) {
  short8 o;
  o[0] = (short)f2bfs(a.x); o[1] = (short)f2bfs(a.y);
  o[2] = (short)f2bfs(a.z); o[3] = (short)f2bfs(a.w);
  o[4] = (short)f2bfs(b.x); o[5] = (short)f2bfs(b.y);
  o[6] = (short)f2bfs(b.z); o[7] = (short)f2bfs(b.w);
  return o;
}
__device__ __forceinline__ float sigm(float x) { return 1.0f / (1.0f + __expf(-x)); }
__device__ __forceinline__ float tanh_(float x) { return 1.0f - 2.0f / (1.0f + __expf(2.0f * x)); }

// async global->LDS, 16B per lane, linear dest (wave-uniform base + lane*16)
__device__ __forceinline__ void gload16(const void* g, void* l) {
  __builtin_amdgcn_global_load_lds(
      (const __attribute__((address_space(1))) unsigned int*)g,
      (__attribute__((address_space(3))) unsigned int*)l, 16, 0, 0);
}

// coherence-point (sc0 sc1) 2B store: visible device-wide after vmcnt(0)
__device__ __forceinline__ void store_short_coh(unsigned short* p, unsigned int v) {
  asm volatile("global_store_short %0, %1, off sc0 sc1" : : "v"(p), "v"(v) : "memory");
}

// ---------- prep: W_cat = [W_hh | W_ih] bf16, rows permuted gate-interleaved ----------
// gate-col c: gate gi=(c>>4)&3, unit u=((c>>6)<<4)|(c&15) -> orig row gi*256+u
// Also builds wcatX: pre-swizzled LDS image of the W_ih part for k_bigx's
// global_load_lds staging. Image (Nt,kt): chunk i (0..1023) holds
// row r=i>>3, k-chunk cl=(i&7)^(r&7) of W_ih cols kt*64+cl*8..+8.
__global__ __launch_bounds__(256) void k_prep(
    const float* __restrict__ Wih, const float* __restrict__ Whh,
    const float* __restrict__ bih, const float* __restrict__ bhh,
    unsigned short* __restrict__ wcat, unsigned short* __restrict__ wcatX,
    float* __restrict__ bias)
{
  int c = blockIdx.x;
  int gi = (c >> 4) & 3;
  int u = ((c >> 6) << 4) | (c & 15);
  int orig = gi * HDIM + u;
  for (int k = threadIdx.x; k < 1024; k += 256) {
    float w = (k < HDIM) ? Whh[(size_t)orig * HDIM + k]
                         : Wih[(size_t)orig * SKEP + (k - HDIM)];
    wcat[(size_t)c * 1024 + k] = f2bfs(w);
  }
  const int NtX = c >> 7, rrX = c & 127;
  for (int kcol = threadIdx.x; kcol < SKEP; kcol += 256) {
    int kt = kcol >> 6, kk = kcol & 63, cl = kk >> 3, e = kk & 7;
    int i = rrX * 8 + (cl ^ (rrX & 7));
    wcatX[(size_t)(NtX * 12 + kt) * 8192 + i * 8 + e] =
        f2bfs(Wih[(size_t)orig * SKEP + kcol]);
  }
  if (threadIdx.x == 0) bias[c] = bih[orig] + bhh[orig];
}

// ---------- k_bigx (t-major): X = hist[:, t, :] @ W_ih^T for all t ----------
// Block = (t, Mtu, Nt). Output slab = ((t*32+Mtu)*8+Nt)*16384 ushorts; thread
// stores 32 accs at slab+tid*32, idx = mi*16+q*4+nj (k_lstm reads 1:1).
// B staged via global_load_lds from pre-swizzled wcatX; A reg-staged (fp32->bf16).
__global__ __launch_bounds__(512) void k_bigx(
    const float* __restrict__ hist,
    const unsigned short* __restrict__ wcatX,
    unsigned short* __restrict__ X)
{
  __shared__ __align__(16) unsigned char smem[65536];
  unsigned char* const A0 = smem;
  unsigned char* const B0 = smem + 16384;
  unsigned char* const A1 = smem + 32768;
  unsigned char* const B1 = smem + 49152;

  const int tid = threadIdx.x;
  const int lane = tid & 63;
  const int wid = tid >> 6;
  const int wr = wid >> 1;       // 0..3
  const int wc = wid & 1;        // 0..1
  const int lr = lane & 15;
  const int lg = lane >> 4;

  const int d = blockIdx.x;
  const int x = d & 7;
  const int Nt = (d >> 3) & 7;
  const int g = ((d >> 6) << 3) | x;          // 0..2047 group id
  const int t = g >> 5;                       // 0..63
  const int Mtu = g & 31;                     // 0..31
  const int n0 = Mtu * 128;
  const int c0 = Nt * 128;

  f32x4 acc[2][4];
#pragma unroll
  for (int mi = 0; mi < 2; ++mi)
#pragma unroll
    for (int nj = 0; nj < 4; ++nj) acc[mi][nj] = f32x4{0.f, 0.f, 0.f, 0.f};

  const int rr = tid >> 3;                    // 0..63
  const int cl = (tid & 7) ^ (rr & 7);        // XOR swizzle chunk (A side)
  const size_t hA0 = ((size_t)(n0 + rr) * T_STEPS + t) * SKEP + (size_t)cl * 8;
  const size_t hA1 = ((size_t)(n0 + rr + 64) * T_STEPS + t) * SKEP + (size_t)cl * 8;
  const int dst0 = tid * 16, dst1 = tid * 16 + 8192;

  // prologue: stage kt=0 (B async via gload_lds, A via regs)
  {
    const unsigned short* img = wcatX + (size_t)(Nt * 12) * 8192;
    gload16(img + (size_t)tid * 8, B0 + wid * 1024);
    gload16(img + (size_t)(tid + 512) * 8, B0 + 8192 + wid * 1024);
    const float* p0 = hist + hA0;
    const float* p1 = hist + hA1;
    float4 f00 = *(const float4*)p0, f01 = *(const float4*)(p0 + 4);
    float4 f10 = *(const float4*)p1, f11 = *(const float4*)(p1 + 4);
    *(short8*)(A0 + dst0) = pack8(f00, f01);
    *(short8*)(A0 + dst1) = pack8(f10, f11);
  }
  __syncthreads();

  for (int kt = 0; kt < 12; ++kt) {
    unsigned char* curA = (kt & 1) ? A1 : A0;
    unsigned char* curB = (kt & 1) ? B1 : B0;
    unsigned char* nxtA = (kt & 1) ? A0 : A1;
    unsigned char* nxtB = (kt & 1) ? B0 : B1;
    const int kn = kt + 1;
    const bool have = (kn < 12);

    float4 f00, f01, f10, f11;
    if (have) {
      const unsigned short* img = wcatX + (size_t)(Nt * 12 + kn) * 8192;
      gload16(img + (size_t)tid * 8, nxtB + wid * 1024);
      gload16(img + (size_t)(tid + 512) * 8, nxtB + 8192 + wid * 1024);
      const float* p0 = hist + hA0 + (size_t)kn * 64;
      const float* p1 = hist + hA1 + (size_t)kn * 64;
      f00 = *(const float4*)p0; f01 = *(const float4*)(p0 + 4);
      f10 = *(const float4*)p1; f11 = *(const float4*)(p1 + 4);
    }

#pragma unroll
    for (int ks = 0; ks < 2; ++ks) {
      short8 av[2], bv[4];
#pragma unroll
      for (int mi = 0; mi < 2; ++mi) {
        int r = wr * 32 + mi * 16 + lr;
        int c = ks * 4 + lg;
        int ph = c ^ (r & 7);
        av[mi] = *(const short8*)(curA + r * 128 + ph * 16);
      }
#pragma unroll
      for (int nj = 0; nj < 4; ++nj) {
        int r = wc * 64 + nj * 16 + lr;
        int c = ks * 4 + lg;
        int ph = c ^ (r & 7);
        bv[nj] = *(const short8*)(curB + r * 128 + ph * 16);
      }
#pragma unroll
      for (int mi = 0; mi < 2; ++mi)
#pragma unroll
        for (int nj = 0; nj < 4; ++nj)
          acc[mi][nj] = __builtin_amdgcn_mfma_f32_16x16x32_bf16(av[mi], bv[nj], acc[mi][nj], 0, 0, 0);
    }

    if (have) {
      *(short8*)(nxtA + dst0) = pack8(f00, f01);
      *(short8*)(nxtA + dst1) = pack8(f10, f11);
    }
    __syncthreads();   // drains vmcnt (gload_lds) + lgkm before buffer swap
  }

  // epilogue: pack 32 accs -> one contiguous 64 B chunk per thread
  unsigned short ob[32];
#pragma unroll
  for (int mi = 0; mi < 2; ++mi)
#pragma unroll
    for (int q = 0; q < 4; ++q)
#pragma unroll
      for (int nj = 0; nj < 4; ++nj)
        ob[mi * 16 + q * 4 + nj] = f2bfs(acc[mi][nj][q]);

  const size_t slab = (((size_t)t * 32 + Mtu) * 8 + Nt) * 16384 + (size_t)tid * 32;
#pragma unroll
  for (int j2 = 0; j2 < 4; ++j2)
    *(short8*)(X + slab + j2 * 8) = *(const short8*)(ob + j2 * 8);
}

// ---------- k_lstm: persistent, all 64 steps, fence-free sync ----------
// 256 blocks (Mt x Nt), 512 threads, 128 KB LDS -> 1 block/CU, all co-resident.
// h exchange entirely through coherence-point (sc1) accesses: producer stores
// h via global_store_short sc0 sc1 + vmcnt(0) drain; counter = relaxed agent
// atomics; consumer h-loads = relaxed agent b64 atomics (bypass stale L1/L2).
// NO cache-maintenance fences anywhere (round-4 lesson: wbl2/inv storms).
__global__ __launch_bounds__(512, 1) void k_lstm(
    const unsigned short* __restrict__ X,
    unsigned short* __restrict__ h0,
    unsigned short* __restrict__ h1,
    const unsigned short* __restrict__ wcat,
    const float* __restrict__ bias,
    const int* __restrict__ lengths,
    unsigned int* __restrict__ ctr)
{
  __shared__ __align__(16) unsigned char smem[131072];
  unsigned char* const Bs = smem;            // 64 KB: 128 gatecols x 512 B (XOR-swizzled)
  unsigned char* const As = smem + 65536;    // 64 KB: 128 users   x 512 B (XOR-swizzled)

  const int tid = threadIdx.x;
  const int lane = tid & 63;
  const int wid = tid >> 6;
  const int wr = wid >> 1, wc = wid & 1;
  const int lr = lane & 15, lg = lane >> 4;
  const int d = blockIdx.x;
  const int Mt = d & 31, Nt = d >> 5;        // d%8 == Mt%8: stripe shares XCD
  const int n0 = Mt * 128, c0 = Nt * 128;
  unsigned int* const ctrp = ctr + Mt * 16;  // 64 B padded counters

  // ---- stage B once: g-linear (coalesced global, conflict-free LDS) ----
#pragma unroll
  for (int j = 0; j < 8; ++j) {
    int g = wid * 512 + j * 64 + lane;       // chunk id 0..4095
    int r = g >> 5, c = g & 31;
    short8 v = *(const short8*)(wcat + (size_t)(c0 + r) * 1024 + c * 8);
    *(short8*)(Bs + r * 512 + ((c ^ (r & 7)) << 4)) = v;
  }

  // ---- per-thread constants ----
  float bs4[4];
#pragma unroll
  for (int gi2 = 0; gi2 < 4; ++gi2) bs4[gi2] = bias[c0 + wc * 64 + gi2 * 16 + lr];
  const int unitg = Nt * 32 + wc * 16 + lr;
  int len8[2][4];
#pragma unroll
  for (int mi = 0; mi < 2; ++mi)
#pragma unroll
    for (int q = 0; q < 4; ++q)
      len8[mi][q] = lengths[n0 + wr * 32 + mi * 16 + lg * 4 + q];

  float cc8[2][4] = {{0.f, 0.f, 0.f, 0.f}, {0.f, 0.f, 0.f, 0.f}};
  unsigned short hp8[2][4] = {{0, 0, 0, 0}, {0, 0, 0, 0}};

#pragma unroll 1
  for (int t = 0; t < T_STEPS; ++t) {
    // X prefetch (independent of h; overlaps the spin-wait)
    short8 xv0, xv1, xv2, xv3;
    {
      const unsigned short* xp =
          X + (((size_t)t * 32 + Mt) * 8 + Nt) * 16384 + (size_t)tid * 32;
      xv0 = *(const short8*)(xp);
      xv1 = *(const short8*)(xp + 8);
      xv2 = *(const short8*)(xp + 16);
      xv3 = *(const short8*)(xp + 24);
    }

    if (t > 0) {
      if (tid == 0) {
        const unsigned tgt = 8u * (unsigned)t;
        while (__hip_atomic_load(ctrp, __ATOMIC_RELAXED, __HIP_MEMORY_SCOPE_AGENT) < tgt)
          __builtin_amdgcn_s_sleep(2);
      }
      __syncthreads();
    }

    const unsigned short* hin = (t & 1) ? h1 : h0;
    unsigned short* hout = (t & 1) ? h0 : h1;

    // ---- stage A: sc1 b64 loads (coherence point) -> swizzled LDS ----
    {
      const unsigned long long* hsrc =
          (const unsigned long long*)(hin + (size_t)n0 * HDIM);
      unsigned long long hv[16];
#pragma unroll
      for (int j = 0; j < 16; ++j)
        hv[j] = __hip_atomic_load(hsrc + j * 512 + tid,
                                  __ATOMIC_RELAXED, __HIP_MEMORY_SCOPE_AGENT);
#pragma unroll
      for (int j = 0; j < 16; ++j) {
        int g64 = j * 512 + tid;
        int r = g64 >> 6, m = g64 & 63;
        int off = r * 512 + ((((m >> 1) ^ (r & 7))) << 4) + (m & 1) * 8;
        *(unsigned long long*)(As + off) = hv[j];
      }
    }
    __syncthreads();

    // ---- GEMM: gates += h @ W_hh^T ----
    f32x4 acc[2][4];
#pragma unroll
    for (int mi = 0; mi < 2; ++mi)
#pragma unroll
      for (int nj = 0; nj < 4; ++nj) acc[mi][nj] = f32x4{0.f, 0.f, 0.f, 0.f};

#pragma unroll
    for (int ks = 0; ks < 8; ++ks) {
      const int chunk = ks * 4 + lg;
      short8 av0, av1, bv[4];
      {
        int r = wr * 32 + lr;
        av0 = *(const short8*)(As + r * 512 + ((chunk ^ (r & 7)) << 4));
        r += 16;
        av1 = *(const short8*)(As + r * 512 + ((chunk ^ (r & 7)) << 4));
      }
#pragma unroll
      for (int nj = 0; nj < 4; ++nj) {
        int rB = wc * 64 + nj * 16 + lr;
        bv[nj] = *(const short8*)(Bs + rB * 512 + ((chunk ^ (rB & 7)) << 4));
      }
#pragma unroll
      for (int nj = 0; nj < 4; ++nj) {
        acc[0][nj] = __builtin_amdgcn_mfma_f32_16x16x32_bf16(av0, bv[nj], acc[0][nj], 0, 0, 0);
        acc[1][nj] = __builtin_amdgcn_mfma_f32_16x16x32_bf16(av1, bv[nj], acc[1][nj], 0, 0, 0);
      }
    }

    // ---- LSTM cell epilogue (c, h_prev in registers; sc1 h stores) ----
#pragma unroll
    for (int mi = 0; mi < 2; ++mi) {
#pragma unroll
      for (int q = 0; q < 4; ++q) {
        const int idx0 = mi * 16 + q * 4;           // 0,4,8,...,28
        const short8 xs = (idx0 < 8) ? xv0 : (idx0 < 16) ? xv1
                         : (idx0 < 24) ? xv2 : xv3;
        const int sb = idx0 & 7;                    // 0 or 4
        float gi_ = sigm(acc[mi][0][q] + bf2f((unsigned short)xs[sb + 0]) + bs4[0]);
        float gf_ = sigm(acc[mi][1][q] + bf2f((unsigned short)xs[sb + 1]) + bs4[1]);
        float gg_ = tanh_(acc[mi][2][q] + bf2f((unsigned short)xs[sb + 2]) + bs4[2]);
        float go_ = sigm(acc[mi][3][q] + bf2f((unsigned short)xs[sb + 3]) + bs4[3]);
        if (t < len8[mi][q]) {
          float cn = gf_ * cc8[mi][q] + gi_ * gg_;
          cc8[mi][q] = cn;
          hp8[mi][q] = f2bfs(go_ * tanh_(cn));
        }
        store_short_coh(hout + (size_t)(n0 + wr * 32 + mi * 16 + lg * 4 + q) * HDIM + unitg,
                        (unsigned int)hp8[mi][q]);
      }
    }

    asm volatile("s_waitcnt vmcnt(0)" ::: "memory");  // h stores acked at coherence point
    __syncthreads();
    if (t < T_STEPS - 1 && tid == 0)
      __hip_atomic_fetch_add(ctrp, 1u, __ATOMIC_RELAXED, __HIP_MEMORY_SCOPE_AGENT);
  }
}

// ---------- Phase C1: s[n] = dot(cc[cid[n]], uv[n]) / sqrt(H) ----------
__global__ __launch_bounds__(256) void k_scores(
    const float* __restrict__ uv, const float* __restrict__ cc,
    const int* __restrict__ cid, float* __restrict__ s)
{
  int n = blockIdx.x * 4 + (threadIdx.x >> 6);
  int lane = threadIdx.x & 63;
  float4 a = *(const float4*)(uv + (size_t)n * HDIM + lane * 4);
  float4 b = *(const float4*)(cc + (size_t)cid[n] * HDIM + lane * 4);
  float dd = a.x * b.x + a.y * b.y + a.z * b.z + a.w * b.w;
  for (int off = 32; off; off >>= 1) dd += __shfl_down(dd, off);
  if (lane == 0) s[n] = dd * 0.0625f;   // 1/sqrt(256)
}

// ---------- Phase C2: segment softmax + role_senti ----------
__global__ __launch_bounds__(256) void k_role(
    const float* __restrict__ s, const int* __restrict__ cid,
    const unsigned short* __restrict__ hn, float* __restrict__ rs)
{
  __shared__ float sv[N_USERS];
  __shared__ int cv[N_USERS];
  __shared__ float red[256];
  const int k = blockIdx.x, tid = threadIdx.x;
  for (int i = tid; i < N_USERS; i += 256) { sv[i] = s[i]; cv[i] = cid[i]; }
  __syncthreads();
  float m = -3.4e38f;
  for (int i = tid; i < N_USERS; i += 256) if (cv[i] == k) m = fmaxf(m, sv[i]);
  red[tid] = m; __syncthreads();
  for (int st = 128; st; st >>= 1) { if (tid < st) red[tid] = fmaxf(red[tid], red[tid + st]); __syncthreads(); }
  const float smax = red[0];
  __syncthreads();
  float sum = 0.f;
  for (int i = tid; i < N_USERS; i += 256)
    if (cv[i] == k) { float e = __expf(sv[i] - smax); sv[i] = e; sum += e; }
  red[tid] = sum; __syncthreads();
  for (int st = 128; st; st >>= 1) { if (tid < st) red[tid] += red[tid + st]; __syncthreads(); }
  const float den = red[0];
  __syncthreads();
  float a = 0.f;
  for (int i = 0; i < N_USERS; ++i)
    if (cv[i] == k) a += sv[i] * bf2f(hn[(size_t)i * HDIM + tid]);
  rs[(size_t)k * HDIM + tid] = a / den;
}

// ---------- Phase D1: per-head MHA over roles ----------
__global__ __launch_bounds__(256) void k_mha(
    const float* __restrict__ rs,
    const float* __restrict__ Wq, const float* __restrict__ bq,
    const float* __restrict__ Wk, const float* __restrict__ bk,
    const float* __restrict__ Wv, const float* __restrict__ bv,
    float* __restrict__ attout)
{
  __shared__ float q[64][32], kk[64][32], v[64][32];
  __shared__ float att[64][64];
  const int h = blockIdx.x, tid = threadIdx.x;
  for (int idx = tid; idx < 2048; idx += 256) {
    int r = idx >> 5, dd2 = idx & 31;
    int wrow = h * 32 + dd2;
    float aq = bq[wrow], ak = bk[wrow], av = bv[wrow];
    const float* x = rs + (size_t)r * HDIM;
    const float* wq = Wq + (size_t)wrow * HDIM;
    const float* wk = Wk + (size_t)wrow * HDIM;
    const float* wv = Wv + (size_t)wrow * HDIM;
    for (int j = 0; j < HDIM; ++j) {
      float xv = x[j];
      aq += xv * wq[j]; ak += xv * wk[j]; av += xv * wv[j];
    }
    q[r][dd2] = aq; kk[r][dd2] = ak; v[r][dd2] = av;
  }
  __syncthreads();
  for (int idx = tid; idx < 4096; idx += 256) {
    int qr = idx >> 6, kr = idx & 63;
    float sc = 0.f;
    for (int dd2 = 0; dd2 < 32; ++dd2) sc += q[qr][dd2] * kk[kr][dd2];
    att[qr][kr] = sc * 0.17677669529663687f;   // 1/sqrt(32)
  }
  __syncthreads();
  if (tid < 64) {
    float m = -3.4e38f;
    for (int j = 0; j < 64; ++j) m = fmaxf(m, att[tid][j]);
    float sum = 0.f;
    for (int j = 0; j < 64; ++j) { float e = __expf(att[tid][j] - m); att[tid][j] = e; sum += e; }
    float inv = 1.f / sum;
    for (int j = 0; j < 64; ++j) att[tid][j] *= inv;
  }
  __syncthreads();
  for (int idx = tid; idx < 2048; idx += 256) {
    int r = idx >> 5, dd2 = idx & 31;
    float o = 0.f;
    for (int kr = 0; kr < 64; ++kr) o += att[r][kr] * v[kr][dd2];
    attout[(size_t)r * HDIM + h * 32 + dd2] = o;
  }
}

// ---------- Phase D2: mean over roles + Wo projection ----------
__global__ __launch_bounds__(256) void k_out(
    const float* __restrict__ attout, const float* __restrict__ Wo,
    const float* __restrict__ bo, float* __restrict__ out)
{
  __shared__ float m_s[256];
  const int tid = threadIdx.x;
  float mm = 0.f;
  for (int r = 0; r < 64; ++r) mm += attout[(size_t)r * HDIM + tid];
  m_s[tid] = mm * (1.0f / 64.0f);
  __syncthreads();
  float a = bo[tid];
  for (int j = 0; j < HDIM; ++j) a += m_s[j] * Wo[(size_t)tid * HDIM + j];
  out[tid] = a;
}

extern "C" void kernel_launch(void* const* d_in, const int* in_sizes, int n_in,
                              void* d_out, int out_size, void* d_ws, size_t ws_size,
                              hipStream_t stream) {
  const float* hist = (const float*)d_in[0];
  const float* uv   = (const float*)d_in[1];
  const float* cc   = (const float*)d_in[2];
  const float* Wih  = (const float*)d_in[3];
  const float* Whh  = (const float*)d_in[4];
  const float* bih  = (const float*)d_in[5];
  const float* bhh  = (const float*)d_in[6];
  const float* Wq   = (const float*)d_in[7];
  const float* bq   = (const float*)d_in[8];
  const float* Wk   = (const float*)d_in[9];
  const float* bk   = (const float*)d_in[10];
  const float* Wv   = (const float*)d_in[11];
  const float* bv   = (const float*)d_in[12];
  const float* Wo   = (const float*)d_in[13];
  const float* bo   = (const float*)d_in[14];
  const int* lengths = (const int*)d_in[15];
  const int* cid     = (const int*)d_in[16];
  float* out = (float*)d_out;

  unsigned char* ws = (unsigned char*)d_ws;
  unsigned short* hbuf0 = (unsigned short*)(ws);                         // 2 MB
  unsigned short* hbuf1 = (unsigned short*)(ws + (1ull << 21));          // 2 MB
  unsigned int*   ctr   = (unsigned int*)  (ws + (2ull << 21));          // 4 KB (64B-padded x32)
  float* bias   = (float*)(ws + (2ull << 21) + 4096);                    // 4 KB
  float* sbuf   = (float*)(ws + (2ull << 21) + 8192);                    // 16 KB
  float* rs     = (float*)(ws + (2ull << 21) + 24576);                   // 64 KB
  float* attout = (float*)(ws + (2ull << 21) + 90112);                   // 64 KB
  unsigned short* wcat  = (unsigned short*)(ws + (5ull << 20));          // 2 MB
  unsigned short* wcatX = (unsigned short*)(ws + (7ull << 20));          // 1.5 MB
  unsigned short* Xbuf  = (unsigned short*)(ws + (16ull << 20));         // 512 MB
  const size_t need = (16ull << 20) + (size_t)N_USERS * T_STEPS * 1024 * 2;
  if (ws_size < need) return;

  hipMemsetAsync(hbuf0, 0, (size_t)N_USERS * HDIM * 2, stream);
  hipMemsetAsync(ctr, 0, 4096, stream);

  k_prep<<<1024, 256, 0, stream>>>(Wih, Whh, bih, bhh, wcat, wcatX, bias);
  k_bigx<<<16384, 512, 0, stream>>>(hist, wcatX, Xbuf);
  k_lstm<<<256, 512, 0, stream>>>(Xbuf, hbuf0, hbuf1, wcat, bias, lengths, ctr);
  // t=63 writes hbuf0 -> final h in hbuf0

  k_scores<<<1024, 256, 0, stream>>>(uv, cc, cid, sbuf);
  k_role<<<64, 256, 0, stream>>>(sbuf, cid, hbuf0, rs);
  k_mha<<<8, 256, 0, stream>>>(rs, Wq, bq, Wk, bk, Wv, bv, attout);
  k_out<<<1, 256, 0, stream>>>(attout, Wo, bo, out);
}